// Round 1
// baseline (80.755 us; speedup 1.0000x reference)
//
#include <hip/hip_runtime.h>
#include <cmath>

#define NPTS 12288
#define NB   64
#define NCH  9
#define NKC  10
#define BIGF 1000000.0f
#define SENT 1e30f

// ---------------------------------------------------------------------------
// K1: per (chunk, batch) block, 9 waves; wave w = channel w (0..7 kpts, 8 cpt).
// Each lane keeps an insertion-sorted top-10 (registers, static idx), then a
// 10-round shuffle pop-min merge produces the wave's top-10 -> workspace.
// ---------------------------------------------------------------------------
__global__ __launch_bounds__(576)
void k1_partial_topk(const float* __restrict__ kpts,  // (64,12288,8,3)
                     const float* __restrict__ cpt,   // (64,12288,1,3)
                     const float* __restrict__ seg,   // (64,12288,2)
                     float* __restrict__ wval,
                     int*   __restrict__ widx,
                     int S)
{
    const int s    = blockIdx.x;
    const int b    = blockIdx.y;
    const int tid  = threadIdx.x;
    const int w    = tid >> 6;     // wave id == channel
    const int lane = tid & 63;
    const int P    = NPTS / S;     // points in this chunk
    const int i0   = s * P;

    extern __shared__ float smask[];   // [P]
    for (int p = tid; p < P; p += 576) {
        const float* sp = seg + ((size_t)b * NPTS + i0 + p) * 2;
        // argmax(seg,-1)==1  <=>  seg1 > seg0 (ties -> argmax 0 -> BIG)
        smask[p] = (sp[1] > sp[0]) ? 1.0f : BIGF;
    }
    __syncthreads();

    float v[NKC]; int id[NKC];
#pragma unroll
    for (int j = 0; j < NKC; ++j) { v[j] = SENT; id[j] = 0; }

    const int iters = P >> 6;
    for (int j = 0; j < iters; ++j) {
        const int p = (j << 6) + lane;
        const int i = i0 + p;
        float x, y, z;
        if (w < 8) {
            const float* op = kpts + (((size_t)b * NPTS + i) * 8 + w) * 3;
            x = op[0]; y = op[1]; z = op[2];
        } else {
            const float* op = cpt + ((size_t)b * NPTS + i) * 3;
            x = op[0]; y = op[1]; z = op[2];
        }
        // match np: sqrt(((x*x + y*y) + z*z)) * mask, no fp-contract
        float n2  = __fadd_rn(__fadd_rn(__fmul_rn(x, x), __fmul_rn(y, y)),
                              __fmul_rn(z, z));
        float key = __fmul_rn(sqrtf(n2), smask[p]);
        if (key < v[NKC - 1]) {
            v[NKC - 1] = key; id[NKC - 1] = i;
#pragma unroll
            for (int q = NKC - 1; q > 0; --q) {
                if (v[q] < v[q - 1]) {
                    float tv = v[q]; v[q] = v[q - 1]; v[q - 1] = tv;
                    int   ti = id[q]; id[q] = id[q - 1]; id[q - 1] = ti;
                }
            }
        }
    }

    // 10-round pop-min k-way merge across the wave's 64 sorted lists
    float outv = 0.0f; int outi = 0;
    for (int r = 0; r < NKC; ++r) {
        float cv = v[0]; int ci = id[0]; int cl = lane;
#pragma unroll
        for (int m = 32; m; m >>= 1) {
            float ov = __shfl_xor(cv, m);
            int   oi = __shfl_xor(ci, m);
            int   ol = __shfl_xor(cl, m);
            if (ov < cv || (ov == cv && ol < cl)) { cv = ov; ci = oi; cl = ol; }
        }
        if (lane == cl) {   // winner pops its head (static shift)
#pragma unroll
            for (int q = 0; q < NKC - 1; ++q) { v[q] = v[q + 1]; id[q] = id[q + 1]; }
            v[NKC - 1] = SENT;
        }
        if (lane == r) { outv = cv; outi = ci; }
    }
    if (lane < NKC) {
        size_t o = ((((size_t)b * S + s) * NCH) + w) * NKC + lane;
        wval[o] = outv; widx[o] = outi;
    }
}

// ---------------------------------------------------------------------------
// K2: one block per batch. Threads 0..8: merge chunk partials -> final top-10
// (ascending key = reference top_k order), gather pcld+off, std-filter mean.
// Thread 0: 3x3 one-sided Jacobi SVD (fully unrolled) -> Kabsch R, t.
// ---------------------------------------------------------------------------

#define JROT(P, Q) do {                                                        \
    float aa = G[0][P]*G[0][P] + G[1][P]*G[1][P] + G[2][P]*G[2][P];            \
    float bb = G[0][Q]*G[0][Q] + G[1][Q]*G[1][Q] + G[2][Q]*G[2][Q];            \
    float gg = G[0][P]*G[0][Q] + G[1][P]*G[1][Q] + G[2][P]*G[2][Q];            \
    if (fabsf(gg) > 1e-30f) {                                                  \
        float zeta = (bb - aa) / (2.0f * gg);                                  \
        float tt = copysignf(1.0f, zeta) / (fabsf(zeta) + sqrtf(1.0f + zeta*zeta)); \
        float cc = 1.0f / sqrtf(1.0f + tt * tt);                               \
        float ss = cc * tt;                                                    \
        _Pragma("unroll")                                                      \
        for (int ii = 0; ii < 3; ++ii) {                                       \
            float gp = G[ii][P], gq = G[ii][Q];                                \
            G[ii][P] = cc*gp - ss*gq; G[ii][Q] = ss*gp + cc*gq;                \
            float vp = Vv[ii][P], vq = Vv[ii][Q];                              \
            Vv[ii][P] = cc*vp - ss*vq; Vv[ii][Q] = ss*vp + cc*vq;              \
        }                                                                      \
    }                                                                          \
} while (0)

#define CSWAP(P, Q) do { if (s##P < s##Q) {                                    \
    float t_ = s##P; s##P = s##Q; s##Q = t_;                                   \
    _Pragma("unroll")                                                          \
    for (int ii = 0; ii < 3; ++ii) {                                           \
        t_ = U[ii][P];  U[ii][P]  = U[ii][Q];  U[ii][Q]  = t_;                 \
        t_ = Vv[ii][P]; Vv[ii][P] = Vv[ii][Q]; Vv[ii][Q] = t_;                 \
    }                                                                          \
} } while (0)

__global__ __launch_bounds__(64)
void k2_cluster_svd(const float* __restrict__ pcld,  // (64,12288,3)
                    const float* __restrict__ kpts,
                    const float* __restrict__ cpt,
                    const float* __restrict__ mesh,  // (64,9,3)
                    const float* __restrict__ wval,
                    const int*   __restrict__ widx,
                    float* __restrict__ out,
                    int S)
{
    const int b   = blockIdx.x;
    const int tid = threadIdx.x;
    __shared__ float voted[NCH][3];

    if (tid < NCH) {
        const int c = tid;
        float v[NKC]; int id[NKC];
#pragma unroll
        for (int j = 0; j < NKC; ++j) { v[j] = SENT; id[j] = 0; }
        for (int s = 0; s < S; ++s) {
            size_t base = (((size_t)b * S + s) * NCH + c) * NKC;
#pragma unroll
            for (int q = 0; q < NKC; ++q) {
                float key = wval[base + q]; int ki = widx[base + q];
                if (key < v[NKC - 1]) {
                    v[NKC - 1] = key; id[NKC - 1] = ki;
#pragma unroll
                    for (int t2 = NKC - 1; t2 > 0; --t2) {
                        if (v[t2] < v[t2 - 1]) {
                            float tv = v[t2]; v[t2] = v[t2 - 1]; v[t2 - 1] = tv;
                            int   ti = id[t2]; id[t2] = id[t2 - 1]; id[t2 - 1] = ti;
                        }
                    }
                }
            }
        }
        // gather candidates: cand = pcld[idx] + off[idx, c]
        float cand[3][NKC];
#pragma unroll
        for (int q = 0; q < NKC; ++q) {
            const int i = id[q];
            const float* pp = pcld + ((size_t)b * NPTS + i) * 3;
            const float* op = (c < 8) ? (kpts + (((size_t)b * NPTS + i) * 8 + c) * 3)
                                      : (cpt  + ((size_t)b * NPTS + i) * 3);
            cand[0][q] = __fadd_rn(pp[0], op[0]);
            cand[1][q] = __fadd_rn(pp[1], op[1]);
            cand[2][q] = __fadd_rn(pp[2], op[2]);
        }
        // per-coordinate std filter (population std, strict <, nz counting)
#pragma unroll
        for (int d = 0; d < 3; ++d) {
            float sum = 0.0f;
#pragma unroll
            for (int q = 0; q < NKC; ++q) sum = __fadd_rn(sum, cand[d][q]);
            float mu = sum / 10.0f;
            float var = 0.0f;
#pragma unroll
            for (int q = 0; q < NKC; ++q) {
                float dq = __fsub_rn(cand[d][q], mu);
                var = __fadd_rn(var, __fmul_rn(dq, dq));
            }
            float sd = sqrtf(var / 10.0f);
            float fs = 0.0f; int cnt = 0;
#pragma unroll
            for (int q = 0; q < NKC; ++q) {
                float x = cand[d][q];
                if (fabsf(__fsub_rn(x, mu)) < sd) {
                    fs = __fadd_rn(fs, x);
                    if (x != 0.0f) cnt++;
                }
            }
            float res = fs / (float)(cnt > 0 ? cnt : 1);
            voted[c][d] = res;
            out[768 + ((size_t)b * NCH + c) * 3 + d] = res;  // kpts_voted
        }
    }
    __syncthreads();

    if (tid == 0) {
        float Ax[9], Ay[9], Az[9], Bx[9], By[9], Bz[9];
#pragma unroll
        for (int n = 0; n < 9; ++n) {
            const float* mp = mesh + ((size_t)b * 9 + n) * 3;
            Ax[n] = mp[0]; Ay[n] = mp[1]; Az[n] = mp[2];
            Bx[n] = voted[n][0]; By[n] = voted[n][1]; Bz[n] = voted[n][2];
        }
        float cax = 0, cay = 0, caz = 0, cbx = 0, cby = 0, cbz = 0;
#pragma unroll
        for (int n = 0; n < 9; ++n) {
            cax += Ax[n]; cay += Ay[n]; caz += Az[n];
            cbx += Bx[n]; cby += By[n]; cbz += Bz[n];
        }
        cax /= 9.0f; cay /= 9.0f; caz /= 9.0f;
        cbx /= 9.0f; cby /= 9.0f; cbz /= 9.0f;

        float H[3][3] = {{0,0,0},{0,0,0},{0,0,0}};
#pragma unroll
        for (int n = 0; n < 9; ++n) {
            float a0 = Ax[n]-cax, a1 = Ay[n]-cay, a2 = Az[n]-caz;
            float b0 = Bx[n]-cbx, b1 = By[n]-cby, b2 = Bz[n]-cbz;
            H[0][0]+=a0*b0; H[0][1]+=a0*b1; H[0][2]+=a0*b2;
            H[1][0]+=a1*b0; H[1][1]+=a1*b1; H[1][2]+=a1*b2;
            H[2][0]+=a2*b0; H[2][1]+=a2*b1; H[2][2]+=a2*b2;
        }

        float G[3][3], Vv[3][3];
#pragma unroll
        for (int i = 0; i < 3; ++i)
#pragma unroll
            for (int j = 0; j < 3; ++j) {
                G[i][j]  = H[i][j];
                Vv[i][j] = (i == j) ? 1.0f : 0.0f;
            }
        for (int sw = 0; sw < 12; ++sw) { JROT(0,1); JROT(0,2); JROT(1,2); }

        float s0 = sqrtf(G[0][0]*G[0][0] + G[1][0]*G[1][0] + G[2][0]*G[2][0]);
        float s1 = sqrtf(G[0][1]*G[0][1] + G[1][1]*G[1][1] + G[2][1]*G[2][1]);
        float s2 = sqrtf(G[0][2]*G[0][2] + G[1][2]*G[1][2] + G[2][2]*G[2][2]);
        float r0 = 1.0f / fmaxf(s0, 1e-30f);
        float r1 = 1.0f / fmaxf(s1, 1e-30f);
        float r2 = 1.0f / fmaxf(s2, 1e-30f);
        float U[3][3];
#pragma unroll
        for (int i = 0; i < 3; ++i) {
            U[i][0] = G[i][0] * r0; U[i][1] = G[i][1] * r1; U[i][2] = G[i][2] * r2;
        }
        CSWAP(0, 1); CSWAP(1, 2); CSWAP(0, 1);   // descending singular values

        float R0[3][3];
#pragma unroll
        for (int i = 0; i < 3; ++i)
#pragma unroll
            for (int j = 0; j < 3; ++j)
                R0[i][j] = Vv[i][0]*U[j][0] + Vv[i][1]*U[j][1] + Vv[i][2]*U[j][2];
        float det = R0[0][0]*(R0[1][1]*R0[2][2] - R0[1][2]*R0[2][1])
                  - R0[0][1]*(R0[1][0]*R0[2][2] - R0[1][2]*R0[2][0])
                  + R0[0][2]*(R0[1][0]*R0[2][1] - R0[1][1]*R0[2][0]);
        float dsgn = (det >= 0.0f) ? 1.0f : -1.0f;

        float R[3][3];
#pragma unroll
        for (int i = 0; i < 3; ++i)
#pragma unroll
            for (int j = 0; j < 3; ++j) {
                R[i][j] = Vv[i][0]*U[j][0] + Vv[i][1]*U[j][1] + dsgn*Vv[i][2]*U[j][2];
                out[(size_t)b * 9 + i * 3 + j] = R[i][j];
            }
#pragma unroll
        for (int i = 0; i < 3; ++i) {
            float ti = ((i==0)?cbx:(i==1)?cby:cbz)
                     - (R[i][0]*cax + R[i][1]*cay + R[i][2]*caz);
            out[576 + (size_t)b * 3 + i] = ti;
        }
    }
}

extern "C" void kernel_launch(void* const* d_in, const int* in_sizes, int n_in,
                              void* d_out, int out_size, void* d_ws, size_t ws_size,
                              hipStream_t stream)
{
    const float* pcld = (const float*)d_in[0];
    const float* kpts = (const float*)d_in[1];
    const float* cpt  = (const float*)d_in[2];
    const float* seg  = (const float*)d_in[3];
    const float* mesh = (const float*)d_in[4];
    float* out = (float*)d_out;

    // pick chunk count S (divides 12288; 16 -> 1024 blocks for occupancy)
    int S = 16;
    while (S > 1 && (size_t)NB * S * NCH * NKC * 8ull > ws_size) S >>= 1;

    float* wval = (float*)d_ws;
    int*   widx = (int*)((char*)d_ws + (size_t)NB * S * NCH * NKC * sizeof(float));

    dim3 g1(S, NB), b1(576);
    size_t lds = (size_t)(NPTS / S) * sizeof(float);
    k1_partial_topk<<<g1, b1, lds, stream>>>(kpts, cpt, seg, wval, widx, S);
    k2_cluster_svd<<<NB, 64, 0, stream>>>(pcld, kpts, cpt, mesh, wval, widx, out, S);
}